// Round 4
// baseline (1093.662 us; speedup 1.0000x reference)
//
#include <hip/hip_runtime.h>

constexpr int NF = 512;
constexpr int SCAN_B = 1024;  // elements scanned per scan1 block
constexpr int DPB = 256;      // dsts per bucket (dst >> 8)
constexpr int NCH = 256;      // chunks (one scatter block per chunk)

__device__ __forceinline__ float dot16(const float* a, const float* w, float acc) {
#pragma unroll
  for (int j = 0; j < 16; ++j) acc = fmaf(a[j], w[j], acc);
  return acc;
}

// ---------- bucket partition (no global atomics, no full sort) ----------

// Phase A: per-chunk histogram over dst-buckets -> cnt[b * NCH + chunk]
__global__ __launch_bounds__(256) void countA_kernel(const int* __restrict__ ei,
                                                     int* __restrict__ cnt, int E,
                                                     int chunk, int nbuck) {
  __shared__ int hist[512];
  const int c = blockIdx.x;
  for (int b = threadIdx.x; b < nbuck; b += 256) hist[b] = 0;
  __syncthreads();
  const int base = c * chunk;
  const int lim = min(chunk, E - base);
  for (int i = threadIdx.x; i < lim; i += 256) atomicAdd(&hist[ei[E + base + i] >> 8], 1);
  __syncthreads();
  for (int b = threadIdx.x; b < nbuck; b += 256) cnt[b * NCH + c] = hist[b];
}

// generic 3-phase exclusive scan over m ints
__global__ __launch_bounds__(256) void scan1_kernel(const int* __restrict__ src,
                                                    int* __restrict__ dst,
                                                    int* __restrict__ bsums, int m) {
  __shared__ int s[256];
  const int t = threadIdx.x;
  const int idx = blockIdx.x * SCAN_B + t * 4;
  int4 d = {0, 0, 0, 0};
  if (idx + 3 < m) {
    d = *(const int4*)(src + idx);
  } else {
    if (idx + 0 < m) d.x = src[idx + 0];
    if (idx + 1 < m) d.y = src[idx + 1];
    if (idx + 2 < m) d.z = src[idx + 2];
    if (idx + 3 < m) d.w = src[idx + 3];
  }
  const int sum = d.x + d.y + d.z + d.w;
  s[t] = sum;
  __syncthreads();
  for (int off = 1; off < 256; off <<= 1) {
    int val = (t >= off) ? s[t - off] : 0;
    __syncthreads();
    s[t] += val;
    __syncthreads();
  }
  const int excl = s[t] - sum;
  if (t == 255) bsums[blockIdx.x] = s[255];
  if (idx + 0 < m) dst[idx + 0] = excl;
  if (idx + 1 < m) dst[idx + 1] = excl + d.x;
  if (idx + 2 < m) dst[idx + 2] = excl + d.x + d.y;
  if (idx + 3 < m) dst[idx + 3] = excl + d.x + d.y + d.z;
}

__global__ __launch_bounds__(256) void scan2_kernel(const int* __restrict__ bsums,
                                                    int* __restrict__ bscan, int nb) {
  __shared__ int s[256];
  const int t = threadIdx.x;
  const int v = (t < nb) ? bsums[t] : 0;
  s[t] = v;
  __syncthreads();
  for (int off = 1; off < 256; off <<= 1) {
    int val = (t >= off) ? s[t - off] : 0;
    __syncthreads();
    s[t] += val;
    __syncthreads();
  }
  if (t < nb) bscan[t] = s[t] - v;
}

__global__ __launch_bounds__(256) void scan3_kernel(int* __restrict__ dst,
                                                    const int* __restrict__ bscan,
                                                    int m) {
  const int base = blockIdx.x * SCAN_B;
  const int add = bscan[blockIdx.x];
  for (int i = threadIdx.x; i < SCAN_B; i += 256) {
    const int idx = base + i;
    if (idx < m) dst[idx] += add;
  }
}

// Phase C: partition edges into dst-buckets. pairs[pos] = (src | dstlow<<17, w).
__global__ __launch_bounds__(256) void scatterC_kernel(
    const int* __restrict__ ei, const float* __restrict__ ew,
    const int* __restrict__ offs, int2* __restrict__ pairs, int E, int chunk,
    int nbuck) {
  __shared__ int cur[512];
  const int c = blockIdx.x;
  for (int b = threadIdx.x; b < nbuck; b += 256) cur[b] = offs[b * NCH + c];
  __syncthreads();
  const int base = c * chunk;
  const int lim = min(chunk, E - base);
  for (int i = threadIdx.x; i < lim; i += 256) {
    const int e = base + i;
    const int s = ei[e];
    const int d = ei[E + e];
    const float w = ew[e];
    const int pos = atomicAdd(&cur[d >> 8], 1);
    pairs[pos] = make_int2(s | ((d & (DPB - 1)) << 17), __float_as_int(w));
  }
}

// ---------- big GEMM: sup1 = x @ W1, pitch-16 output ----------

template <int COUT, int POUT>
__global__ __launch_bounds__(256) void gemm_big_kernel(const float* __restrict__ x,
                                                       const float* __restrict__ W,
                                                       float* __restrict__ sup, int n) {
  __shared__ __align__(16) float sW[COUT][NF];
  for (int i = threadIdx.x; i < COUT * NF; i += 256) {
    int c = i / NF, k = i - c * NF;
    sW[c][k] = W[(size_t)k * COUT + c];
  }
  __syncthreads();

  const int v = blockIdx.x * 256 + threadIdx.x;
  if (v >= n) return;

  float acc[COUT];
#pragma unroll
  for (int c = 0; c < COUT; ++c) acc[c] = 0.f;

  const float4* xr = (const float4*)(x + (size_t)v * NF);
  for (int kb = 0; kb < NF / 16; ++kb) {
    float4 aq[4];
#pragma unroll
    for (int j = 0; j < 4; ++j) aq[j] = xr[kb * 4 + j];
    const float* af = (const float*)aq;
#pragma unroll
    for (int c = 0; c < COUT; ++c) {
      const float4* wr = (const float4*)(&sW[c][kb * 16]);
      float4 wq[4];
#pragma unroll
      for (int j = 0; j < 4; ++j) wq[j] = wr[j];
      acc[c] = dot16(af, (const float*)wq, acc[c]);
    }
  }

  __align__(16) float outv[POUT];
#pragma unroll
  for (int c = 0; c < POUT; ++c) outv[c] = (c < COUT) ? acc[c] : 0.f;
  float* o = sup + (size_t)v * POUT;
#pragma unroll
  for (int g = 0; g < POUT / 4; ++g) ((float4*)o)[g] = ((float4*)outv)[g];
}

// ---------- fused aggregate(+bias) + next-layer GEMM ----------
// Block b owns nodes [b*256, b*256+256). LDS agg accumulated via ds_add_f32
// from the bucket's packed pairs, then out = (agg [+ bagg]) [@ W [+ bout]].
template <int PIN, int CIN, int COUT, int POUT, bool AGG_BIAS, bool OUT_BIAS,
          bool IDENT>
__global__ __launch_bounds__(512) void agg_gemm_kernel(
    const int* __restrict__ offs, const int2* __restrict__ pairs,
    const float* __restrict__ sup, const float* __restrict__ bagg,
    const float* __restrict__ W, const float* __restrict__ bout,
    float* __restrict__ outp, int n, int nbuck, int E) {
  __shared__ float agg[DPB][PIN];
  __shared__ float sW[IDENT ? 1 : CIN * COUT];
  __shared__ float sba[CIN];
  __shared__ float sbo[COUT];
  const int t = threadIdx.x;
  const int b = blockIdx.x;

  for (int i = t; i < DPB * PIN; i += 512) ((float*)agg)[i] = 0.f;
  if constexpr (!IDENT)
    for (int i = t; i < CIN * COUT; i += 512) sW[i] = W[i];
  if constexpr (AGG_BIAS)
    if (t < CIN) sba[t] = bagg[t];
  if constexpr (OUT_BIAS)
    if (t < COUT) sbo[t] = bout[t];
  __syncthreads();

  const int base = offs[b * NCH];
  const int end = (b + 1 < nbuck) ? offs[(b + 1) * NCH] : E;
  for (int i = base + t; i < end; i += 512) {
    const int2 p = pairs[i];
    const float w = __int_as_float(p.y);
    const int src = p.x & 0x1FFFF;
    const int dl = (p.x >> 17) & (DPB - 1);
    const float4* hr = (const float4*)(sup + (size_t)src * PIN);
    float4 q[PIN / 4];
#pragma unroll
    for (int g = 0; g < PIN / 4; ++g) q[g] = hr[g];
    const float* hv = (const float*)q;
#pragma unroll
    for (int c = 0; c < CIN; ++c) atomicAdd(&agg[dl][c], w * hv[c]);
  }
  __syncthreads();

  if (t < DPB) {
    const int v = b * DPB + t;
    if (v < n) {
      float h[CIN];
#pragma unroll
      for (int c = 0; c < CIN; ++c)
        h[c] = agg[t][c] + (AGG_BIAS ? sba[c] : 0.f);
      __align__(16) float outv[POUT];
      if constexpr (IDENT) {
#pragma unroll
        for (int c = 0; c < POUT; ++c) outv[c] = (c < CIN) ? h[c] : 0.f;
      } else {
#pragma unroll
        for (int j = 0; j < COUT; ++j) {
          float a = OUT_BIAS ? sbo[j] : 0.f;
#pragma unroll
          for (int k = 0; k < CIN; ++k) a = fmaf(h[k], sW[k * COUT + j], a);
          outv[j] = a;
        }
#pragma unroll
        for (int j = COUT; j < POUT; ++j) outv[j] = 0.f;
      }
      float* o = outp + (size_t)v * POUT;
#pragma unroll
      for (int g = 0; g < POUT / 4; ++g) ((float4*)o)[g] = ((float4*)outv)[g];
    }
  }
}

extern "C" void kernel_launch(void* const* d_in, const int* in_sizes, int n_in,
                              void* d_out, int out_size, void* d_ws,
                              size_t ws_size, hipStream_t stream) {
  const float* x = (const float*)d_in[0];
  const int* ei = (const int*)d_in[1];
  const float* ew = (const float*)d_in[2];
  const float* W1 = (const float*)d_in[3];
  const float* b1 = (const float*)d_in[4];
  const float* W2 = (const float*)d_in[5];
  const float* b2 = (const float*)d_in[6];
  const float* W3 = (const float*)d_in[7];
  const float* b3 = (const float*)d_in[8];
  const float* W4 = (const float*)d_in[9];
  const float* b4 = (const float*)d_in[10];
  const float* W5 = (const float*)d_in[11];
  const float* b5 = (const float*)d_in[12];
  const float* W6 = (const float*)d_in[13];
  const float* b6 = (const float*)d_in[14];
  float* out = (float*)d_out;

  const int n = in_sizes[0] / NF;  // 100000
  const int E = in_sizes[2];       // 3200000

  const int nbuck = (n + DPB - 1) / DPB;   // 391
  const int chunk = (E + NCH - 1) / NCH;   // 12500
  const int M = nbuck * NCH;               // 100096
  const int Mpad = (M + 3) & ~3;

  // workspace layout (16B aligned)
  float* A = (float*)d_ws;                 // n*16
  float* B = A + (size_t)n * 16;           // n*16
  int* cnt = (int*)(B + (size_t)n * 16);   // Mpad
  int* offs = cnt + Mpad;                  // Mpad
  int* bsums = offs + Mpad;                // 256
  int* bscan = bsums + 256;                // 256
  uintptr_t up = (uintptr_t)(bscan + 256);
  up = (up + 15) & ~(uintptr_t)15;
  int2* pairs = (int2*)up;                 // E

  const int gn256 = (n + 255) / 256;
  const int nsb = (M + SCAN_B - 1) / SCAN_B;  // 98

  // ---- bucket partition (zero global atomics) ----
  countA_kernel<<<NCH, 256, 0, stream>>>(ei, cnt, E, chunk, nbuck);
  scan1_kernel<<<nsb, 256, 0, stream>>>(cnt, offs, bsums, M);
  scan2_kernel<<<1, 256, 0, stream>>>(bsums, bscan, nsb);
  scan3_kernel<<<nsb, 256, 0, stream>>>(offs, bscan, M);
  scatterC_kernel<<<NCH, 256, 0, stream>>>(ei, ew, offs, pairs, E, chunk, nbuck);

  // ---- L1: sup1 = x@W1 (pitch 16) ----
  gemm_big_kernel<12, 16><<<gn256, 256, 0, stream>>>(x, W1, A, n);

  // ---- fused layers: agg(sup_k)+b_k -> @W_{k+1} -> sup_{k+1} ----
  // F1: agg(A,12)+b1 @W2(12x10) -> B pitch16
  agg_gemm_kernel<16, 12, 10, 16, true, false, false>
      <<<nbuck, 512, 0, stream>>>(offs, pairs, A, b1, W2, nullptr, B, n, nbuck, E);
  // F2: agg(B,10)+b2 @W3(10x8) -> A pitch8
  agg_gemm_kernel<16, 10, 8, 8, true, false, false>
      <<<nbuck, 512, 0, stream>>>(offs, pairs, B, b2, W3, nullptr, A, n, nbuck, E);
  // F3: agg(A,8)+b3 @W4(8x6) -> B pitch8
  agg_gemm_kernel<8, 8, 6, 8, true, false, false>
      <<<nbuck, 512, 0, stream>>>(offs, pairs, A, b3, W4, nullptr, B, n, nbuck, E);
  // F4: agg(B,6)+b4 @W5(6x4) -> A pitch4
  agg_gemm_kernel<8, 6, 4, 4, true, false, false>
      <<<nbuck, 512, 0, stream>>>(offs, pairs, B, b4, W5, nullptr, A, n, nbuck, E);
  // F5: h5 = agg(A,4)+b5 -> B pitch4 (identity)
  agg_gemm_kernel<4, 4, 4, 4, true, false, true>
      <<<nbuck, 512, 0, stream>>>(offs, pairs, A, b5, nullptr, nullptr, B, n, nbuck, E);
  // F6: agg(B,4) @W6(4x16)+b6 -> out (aggregate-first for layer 6)
  agg_gemm_kernel<4, 4, 16, 16, false, true, false>
      <<<nbuck, 512, 0, stream>>>(offs, pairs, B, nullptr, W6, b6, out, n, nbuck, E);
}

// Round 5
// 392.490 us; speedup vs baseline: 2.7865x; 2.7865x over previous
//
#include <hip/hip_runtime.h>

constexpr int NF = 512;
constexpr int SCAN_B = 1024;  // elements scanned per scan1 block
constexpr int DPB = 256;      // dsts per bucket (dst >> 8)
constexpr int CHUNK = 16384;  // edges per partition block
constexpr int BMAX = 9216;    // max edges per bucket staged in LDS (mean 8184, +11 sigma)

__device__ __forceinline__ float dot16(const float* a, const float* w, float acc) {
#pragma unroll
  for (int j = 0; j < 16; ++j) acc = fmaf(a[j], w[j], acc);
  return acc;
}

// ---------- CSR build: atomic-free two-level counting sort (round-3 proven) ----------

__global__ __launch_bounds__(256) void countA_kernel(const int* __restrict__ ei,
                                                     int* __restrict__ cnt, int E,
                                                     int nbuck, int nch) {
  __shared__ int hist[512];
  const int c = blockIdx.x;
  for (int b = threadIdx.x; b < nbuck; b += 256) hist[b] = 0;
  __syncthreads();
  const int base = c * CHUNK;
  for (int i = threadIdx.x; i < CHUNK; i += 256) {
    const int e = base + i;
    if (e < E) atomicAdd(&hist[ei[E + e] >> 8], 1);
  }
  __syncthreads();
  for (int b = threadIdx.x; b < nbuck; b += 256) cnt[b * nch + c] = hist[b];
}

__global__ __launch_bounds__(256) void scan1_kernel(const int* __restrict__ src,
                                                    int* __restrict__ dst,
                                                    int* __restrict__ bsums, int m) {
  __shared__ int s[256];
  const int t = threadIdx.x;
  const int idx = blockIdx.x * SCAN_B + t * 4;
  int4 d = {0, 0, 0, 0};
  if (idx + 3 < m) {
    d = *(const int4*)(src + idx);
  } else {
    if (idx + 0 < m) d.x = src[idx + 0];
    if (idx + 1 < m) d.y = src[idx + 1];
    if (idx + 2 < m) d.z = src[idx + 2];
    if (idx + 3 < m) d.w = src[idx + 3];
  }
  const int sum = d.x + d.y + d.z + d.w;
  s[t] = sum;
  __syncthreads();
  for (int off = 1; off < 256; off <<= 1) {
    int val = (t >= off) ? s[t - off] : 0;
    __syncthreads();
    s[t] += val;
    __syncthreads();
  }
  const int excl = s[t] - sum;
  if (t == 255) bsums[blockIdx.x] = s[255];
  if (idx + 0 < m) dst[idx + 0] = excl;
  if (idx + 1 < m) dst[idx + 1] = excl + d.x;
  if (idx + 2 < m) dst[idx + 2] = excl + d.x + d.y;
  if (idx + 3 < m) dst[idx + 3] = excl + d.x + d.y + d.z;
}

__global__ __launch_bounds__(256) void scan2_kernel(const int* __restrict__ bsums,
                                                    int* __restrict__ bscan, int nb) {
  __shared__ int s[256];
  const int t = threadIdx.x;
  const int v = (t < nb) ? bsums[t] : 0;
  s[t] = v;
  __syncthreads();
  for (int off = 1; off < 256; off <<= 1) {
    int val = (t >= off) ? s[t - off] : 0;
    __syncthreads();
    s[t] += val;
    __syncthreads();
  }
  if (t < nb) bscan[t] = s[t] - v;
}

__global__ __launch_bounds__(256) void scan3_kernel(int* __restrict__ dst,
                                                    const int* __restrict__ bscan,
                                                    int m) {
  const int base = blockIdx.x * SCAN_B;
  const int add = bscan[blockIdx.x];
  for (int i = threadIdx.x; i < SCAN_B; i += 256) {
    const int idx = base + i;
    if (idx < m) dst[idx] += add;
  }
}

__global__ __launch_bounds__(256) void scatterC_kernel(
    const int* __restrict__ ei, const float* __restrict__ ew,
    const int* __restrict__ offs, int2* __restrict__ pairs, int E, int nbuck,
    int nch) {
  __shared__ int cur[512];
  const int c = blockIdx.x;
  for (int b = threadIdx.x; b < nbuck; b += 256) cur[b] = offs[b * nch + c];
  __syncthreads();
  const int base = c * CHUNK;
  for (int i = threadIdx.x; i < CHUNK; i += 256) {
    const int e = base + i;
    if (e >= E) break;
    const int s = ei[e];
    const int d = ei[E + e];
    const float w = ew[e];
    const int pos = atomicAdd(&cur[d >> 8], 1);
    pairs[pos] = make_int2(s | ((d & (DPB - 1)) << 17), __float_as_int(w));
  }
}

__global__ __launch_bounds__(256) void bucketD_kernel(const int* __restrict__ offs,
                                                      int2* __restrict__ pairs,
                                                      int* __restrict__ rowptr, int n,
                                                      int E, int nbuck, int nch) {
  __shared__ int2 stage[BMAX];
  __shared__ int h[DPB];
  __shared__ int s[DPB];
  __shared__ int cur[DPB];
  const int b = blockIdx.x;
  const int t = threadIdx.x;
  if (b == 0 && t == 0) rowptr[n] = E;
  const int base = offs[b * nch];
  const int end = (b + 1 < nbuck) ? offs[(b + 1) * nch] : E;
  const int cnt = end - base;

  for (int i = t; i < DPB; i += 256) h[i] = 0;
  __syncthreads();
  for (int i = t; i < cnt; i += 256) {
    const int2 p = pairs[base + i];
    atomicAdd(&h[(p.x >> 17) & (DPB - 1)], 1);
  }
  __syncthreads();
  const int own = h[t];
  s[t] = own;
  __syncthreads();
  for (int off = 1; off < 256; off <<= 1) {
    int val = (t >= off) ? s[t - off] : 0;
    __syncthreads();
    s[t] += val;
    __syncthreads();
  }
  const int excl = s[t] - own;
  cur[t] = excl;
  const int dst = b * DPB + t;
  if (dst < n) rowptr[dst] = base + excl;
  __syncthreads();
  for (int i = t; i < cnt; i += 256) {
    const int2 p = pairs[base + i];
    const int r = atomicAdd(&cur[(p.x >> 17) & (DPB - 1)], 1);
    if (r < BMAX) stage[r] = make_int2(p.x & 0x1FFFF, p.y);
  }
  __syncthreads();
  const int lim = cnt < BMAX ? cnt : BMAX;
  for (int i = t; i < lim; i += 256) pairs[base + i] = stage[i];
}

// ---------- big GEMM: sup1 = x @ W1, pitch-POUT output, double-buffered loads ----------

template <int COUT, int POUT>
__global__ __launch_bounds__(256) void gemm_big_kernel(const float* __restrict__ x,
                                                       const float* __restrict__ W,
                                                       float* __restrict__ sup, int n) {
  __shared__ __align__(16) float sW[COUT][NF];
  for (int i = threadIdx.x; i < COUT * NF; i += 256) {
    int c = i / NF, k = i - c * NF;
    sW[c][k] = W[(size_t)k * COUT + c];
  }
  __syncthreads();

  const int v = blockIdx.x * 256 + threadIdx.x;
  if (v >= n) return;

  float acc[COUT];
#pragma unroll
  for (int c = 0; c < COUT; ++c) acc[c] = 0.f;

  const float4* xr = (const float4*)(x + (size_t)v * NF);
  float4 cur[4], nxt[4];
#pragma unroll
  for (int j = 0; j < 4; ++j) cur[j] = xr[j];

  for (int kb = 0; kb < NF / 16; ++kb) {
    const int kn = (kb + 1 < NF / 16) ? kb + 1 : kb;
#pragma unroll
    for (int j = 0; j < 4; ++j) nxt[j] = xr[kn * 4 + j];
    const float* af = (const float*)cur;
#pragma unroll
    for (int c = 0; c < COUT; ++c) {
      const float4* wr = (const float4*)(&sW[c][kb * 16]);
      float4 wq[4];
#pragma unroll
      for (int j = 0; j < 4; ++j) wq[j] = wr[j];
      acc[c] = dot16(af, (const float*)wq, acc[c]);
    }
#pragma unroll
    for (int j = 0; j < 4; ++j) cur[j] = nxt[j];
  }

  __align__(16) float outv[POUT];
#pragma unroll
  for (int c = 0; c < POUT; ++c) outv[c] = (c < COUT) ? acc[c] : 0.f;
  float* o = sup + (size_t)v * POUT;
#pragma unroll
  for (int g = 0; g < POUT / 4; ++g) ((float4*)o)[g] = ((float4*)outv)[g];
}

// ---------- fused pull + next-layer GEMM ----------
// Quad (4 lanes) per node: lane-strided edge gather into register acc,
// quad shfl_xor reduce (all 4 lanes end with full agg row), +agg-bias,
// then each lane emits 4 columns of (h @ W) [+ out-bias]. W is staged in
// LDS zero-padded to 16 columns so padded output columns come out 0.
template <int PIN, int CIN, int COUT, int POUT, bool AGG_BIAS, bool OUT_BIAS,
          bool IDENT>
__global__ __launch_bounds__(256) void pull_gemm_kernel(
    const int* __restrict__ rowptr, const int2* __restrict__ pairs,
    const float* __restrict__ sup, const float* __restrict__ bagg,
    const float* __restrict__ W, const float* __restrict__ bout,
    float* __restrict__ outp, int n) {
  constexpr int NQ = (CIN + 3) / 4;  // float4 gathers per edge
  __shared__ float sW[IDENT ? 1 : CIN * 16];
  __shared__ float sba[16];
  __shared__ float sbo[16];
  const int tt = threadIdx.x;
  if constexpr (!IDENT) {
    for (int i = tt; i < CIN * 16; i += 256) {
      const int k = i >> 4, j = i & 15;
      sW[i] = (j < COUT) ? W[k * COUT + j] : 0.f;
    }
  }
  if constexpr (AGG_BIAS)
    if (tt < CIN) sba[tt] = bagg[tt];
  if constexpr (OUT_BIAS)
    if (tt < COUT) sbo[tt] = bout[tt];
  __syncthreads();

  const int t = blockIdx.x * 256 + tt;
  const int v = t >> 2;
  const int lane = t & 3;
  if (v >= n) return;
  const int beg = rowptr[v];
  const int end = rowptr[v + 1];

  float acc[NQ * 4];
#pragma unroll
  for (int c = 0; c < NQ * 4; ++c) acc[c] = 0.f;
  for (int i = beg + lane; i < end; i += 4) {
    const int2 p = pairs[i];
    const float w = __int_as_float(p.y);
    const float4* hr = (const float4*)(sup + (size_t)p.x * PIN);
    float4 q[NQ];
#pragma unroll
    for (int g = 0; g < NQ; ++g) q[g] = hr[g];
    const float* hv = (const float*)q;
#pragma unroll
    for (int c = 0; c < CIN; ++c) acc[c] = fmaf(w, hv[c], acc[c]);
  }
#pragma unroll
  for (int c = 0; c < CIN; ++c) {
    acc[c] += __shfl_xor(acc[c], 1);
    acc[c] += __shfl_xor(acc[c], 2);
    if constexpr (AGG_BIAS) acc[c] += sba[c];
  }

  if constexpr (IDENT) {
    if (lane == 0) {
      float4 o;
      o.x = acc[0]; o.y = acc[1]; o.z = acc[2]; o.w = acc[3];
      *((float4*)(outp + (size_t)v * POUT)) = o;
    }
  } else {
    if (lane * 4 < POUT) {
      const int col = lane * 4;
      float r[4];
#pragma unroll
      for (int j = 0; j < 4; ++j) {
        float a = OUT_BIAS ? sbo[col + j] : 0.f;
#pragma unroll
        for (int k = 0; k < CIN; ++k) a = fmaf(acc[k], sW[k * 16 + col + j], a);
        r[j] = a;
      }
      float4 o;
      o.x = r[0]; o.y = r[1]; o.z = r[2]; o.w = r[3];
      *((float4*)(outp + (size_t)v * POUT + col)) = o;
    }
  }
}

extern "C" void kernel_launch(void* const* d_in, const int* in_sizes, int n_in,
                              void* d_out, int out_size, void* d_ws,
                              size_t ws_size, hipStream_t stream) {
  const float* x = (const float*)d_in[0];
  const int* ei = (const int*)d_in[1];
  const float* ew = (const float*)d_in[2];
  const float* W1 = (const float*)d_in[3];
  const float* b1 = (const float*)d_in[4];
  const float* W2 = (const float*)d_in[5];
  const float* b2 = (const float*)d_in[6];
  const float* W3 = (const float*)d_in[7];
  const float* b3 = (const float*)d_in[8];
  const float* W4 = (const float*)d_in[9];
  const float* b4 = (const float*)d_in[10];
  const float* W5 = (const float*)d_in[11];
  const float* b5 = (const float*)d_in[12];
  const float* W6 = (const float*)d_in[13];
  const float* b6 = (const float*)d_in[14];
  float* out = (float*)d_out;

  const int n = in_sizes[0] / NF;  // 100000
  const int E = in_sizes[2];       // 3200000

  const int nbuck = (n + DPB - 1) / DPB;    // 391
  const int nch = (E + CHUNK - 1) / CHUNK;  // 196
  const int M = nbuck * nch;                // 76636
  const int Mpad = (M + 3) & ~3;

  // workspace layout (16B aligned)
  float* A = (float*)d_ws;                // n*16
  float* B = A + (size_t)n * 16;          // n*16
  int* cnt = (int*)(B + (size_t)n * 16);  // Mpad
  int* offs = cnt + Mpad;                 // Mpad
  int* bsums = offs + Mpad;               // 256
  int* bscan = bsums + 256;               // 256
  int* rowptr = bscan + 256;              // n+1
  uintptr_t up = (uintptr_t)(rowptr + n + 1);
  up = (up + 15) & ~(uintptr_t)15;
  int2* pairs = (int2*)up;                // E

  const int gn256 = (n + 255) / 256;
  const int gq = ((n * 4) + 255) / 256;       // 1563 quad blocks
  const int nsb = (M + SCAN_B - 1) / SCAN_B;  // 75

  // ---- CSR build, zero global atomics ----
  countA_kernel<<<nch, 256, 0, stream>>>(ei, cnt, E, nbuck, nch);
  scan1_kernel<<<nsb, 256, 0, stream>>>(cnt, offs, bsums, M);
  scan2_kernel<<<1, 256, 0, stream>>>(bsums, bscan, nsb);
  scan3_kernel<<<nsb, 256, 0, stream>>>(offs, bscan, M);
  scatterC_kernel<<<nch, 256, 0, stream>>>(ei, ew, offs, pairs, E, nbuck, nch);
  bucketD_kernel<<<nbuck, 256, 0, stream>>>(offs, pairs, rowptr, n, E, nbuck, nch);

  // ---- L1: sup1 = x@W1 -> A (pitch 16) ----
  gemm_big_kernel<12, 16><<<gn256, 256, 0, stream>>>(x, W1, A, n);

  // ---- fused: h_k = pull(sup_k)+b_k ; sup_{k+1} = h_k @ W_{k+1} ----
  // F1: pull(A,12)+b1 @W2(12x10) -> B pitch16
  pull_gemm_kernel<16, 12, 10, 16, true, false, false>
      <<<gq, 256, 0, stream>>>(rowptr, pairs, A, b1, W2, nullptr, B, n);
  // F2: pull(B,10)+b2 @W3(10x8) -> A pitch8
  pull_gemm_kernel<16, 10, 8, 8, true, false, false>
      <<<gq, 256, 0, stream>>>(rowptr, pairs, B, b2, W3, nullptr, A, n);
  // F3: pull(A,8)+b3 @W4(8x6) -> B pitch8
  pull_gemm_kernel<8, 8, 6, 8, true, false, false>
      <<<gq, 256, 0, stream>>>(rowptr, pairs, A, b3, W4, nullptr, B, n);
  // F4: pull(B,6)+b4 @W5(6x4) -> A pitch4
  pull_gemm_kernel<8, 6, 4, 4, true, false, false>
      <<<gq, 256, 0, stream>>>(rowptr, pairs, B, b4, W5, nullptr, A, n);
  // F5: h5 = pull(A,4)+b5 -> B pitch4 (identity)
  pull_gemm_kernel<4, 4, 4, 4, true, false, true>
      <<<gq, 256, 0, stream>>>(rowptr, pairs, A, b5, nullptr, nullptr, B, n);
  // F6: agg6 = pull(B,4); out = agg6@W6 + b6 (aggregate-first layer 6)
  pull_gemm_kernel<4, 4, 16, 16, false, true, false>
      <<<gq, 256, 0, stream>>>(rowptr, pairs, B, nullptr, W6, b6, out, n);
}

// Round 6
// 310.009 us; speedup vs baseline: 3.5278x; 1.2661x over previous
//
#include <hip/hip_runtime.h>
#include <hip/hip_fp16.h>

constexpr int NF = 512;
constexpr int SCAN_B = 1024;  // elements scanned per scan1 block
constexpr int DPB = 256;      // dsts per bucket (dst >> 8)
constexpr int CHUNK = 16384;  // edges per partition block
constexpr int BMAX = 9216;    // max edges per bucket staged in LDS (mean 8184, +11 sigma)

__device__ __forceinline__ float dot16(const float* a, const float* w, float acc) {
#pragma unroll
  for (int j = 0; j < 16; ++j) acc = fmaf(a[j], w[j], acc);
  return acc;
}

// ---------- K1: fused gemm_big (sup1 = x@W1 -> fp16 pitch16) + countA ----------
// Blocks [0, nch) run the per-chunk dst-bucket histogram; blocks [nch, nch+gn)
// run the big GEMM. Independent work, concurrent on the device.
template <int COUT>
__global__ __launch_bounds__(256) void gemm_big_count_kernel(
    const float* __restrict__ x, const float* __restrict__ W,
    __half* __restrict__ sup, int n, const int* __restrict__ ei,
    int* __restrict__ cnt, int E, int nbuck, int nch) {
  __shared__ __align__(16) float smem[COUT * NF];  // 24KB; countA reuses as hist
  if ((int)blockIdx.x < nch) {
    int* hist = (int*)smem;
    const int c = blockIdx.x;
    for (int b = threadIdx.x; b < nbuck; b += 256) hist[b] = 0;
    __syncthreads();
    const int base = c * CHUNK;
    for (int i = threadIdx.x; i < CHUNK; i += 256) {
      const int e = base + i;
      if (e < E) atomicAdd(&hist[ei[E + e] >> 8], 1);
    }
    __syncthreads();
    for (int b = threadIdx.x; b < nbuck; b += 256) cnt[b * nch + c] = hist[b];
    return;
  }

  float(*sW)[NF] = (float(*)[NF])smem;
  for (int i = threadIdx.x; i < COUT * NF; i += 256) {
    int c = i / NF, k = i - c * NF;
    sW[c][k] = W[(size_t)k * COUT + c];
  }
  __syncthreads();

  const int v = (blockIdx.x - nch) * 256 + threadIdx.x;
  if (v >= n) return;

  float acc[COUT];
#pragma unroll
  for (int c = 0; c < COUT; ++c) acc[c] = 0.f;

  const float4* xr = (const float4*)(x + (size_t)v * NF);
  float4 cur[4], nxt[4];
#pragma unroll
  for (int j = 0; j < 4; ++j) cur[j] = xr[j];
  for (int kb = 0; kb < NF / 16; ++kb) {
    const int kn = (kb + 1 < NF / 16) ? kb + 1 : kb;
#pragma unroll
    for (int j = 0; j < 4; ++j) nxt[j] = xr[kn * 4 + j];
    const float* af = (const float*)cur;
#pragma unroll
    for (int c = 0; c < COUT; ++c) {
      const float4* wr = (const float4*)(&sW[c][kb * 16]);
      float4 wq[4];
#pragma unroll
      for (int j = 0; j < 4; ++j) wq[j] = wr[j];
      acc[c] = dot16(af, (const float*)wq, acc[c]);
    }
#pragma unroll
    for (int j = 0; j < 4; ++j) cur[j] = nxt[j];
  }

  // write 12 halves (24B) of the 16-half row
  union { uint4 u; __half2 h[4]; } o1;
  union { uint2 u; __half2 h[2]; } o2;
#pragma unroll
  for (int g = 0; g < 4; ++g) o1.h[g] = __floats2half2_rn(acc[2 * g], acc[2 * g + 1]);
#pragma unroll
  for (int g = 0; g < 2; ++g) o2.h[g] = __floats2half2_rn(acc[8 + 2 * g], acc[9 + 2 * g]);
  __half* o = sup + (size_t)v * 16;
  *(uint4*)o = o1.u;
  *(uint2*)(o + 8) = o2.u;
}

// ---------- scans (round-3 proven) ----------

__global__ __launch_bounds__(256) void scan1_kernel(const int* __restrict__ src,
                                                    int* __restrict__ dst,
                                                    int* __restrict__ bsums, int m) {
  __shared__ int s[256];
  const int t = threadIdx.x;
  const int idx = blockIdx.x * SCAN_B + t * 4;
  int4 d = {0, 0, 0, 0};
  if (idx + 3 < m) {
    d = *(const int4*)(src + idx);
  } else {
    if (idx + 0 < m) d.x = src[idx + 0];
    if (idx + 1 < m) d.y = src[idx + 1];
    if (idx + 2 < m) d.z = src[idx + 2];
    if (idx + 3 < m) d.w = src[idx + 3];
  }
  const int sum = d.x + d.y + d.z + d.w;
  s[t] = sum;
  __syncthreads();
  for (int off = 1; off < 256; off <<= 1) {
    int val = (t >= off) ? s[t - off] : 0;
    __syncthreads();
    s[t] += val;
    __syncthreads();
  }
  const int excl = s[t] - sum;
  if (t == 255) bsums[blockIdx.x] = s[255];
  if (idx + 0 < m) dst[idx + 0] = excl;
  if (idx + 1 < m) dst[idx + 1] = excl + d.x;
  if (idx + 2 < m) dst[idx + 2] = excl + d.x + d.y;
  if (idx + 3 < m) dst[idx + 3] = excl + d.x + d.y + d.z;
}

__global__ __launch_bounds__(256) void scan2_kernel(const int* __restrict__ bsums,
                                                    int* __restrict__ bscan, int nb) {
  __shared__ int s[256];
  const int t = threadIdx.x;
  const int v = (t < nb) ? bsums[t] : 0;
  s[t] = v;
  __syncthreads();
  for (int off = 1; off < 256; off <<= 1) {
    int val = (t >= off) ? s[t - off] : 0;
    __syncthreads();
    s[t] += val;
    __syncthreads();
  }
  if (t < nb) bscan[t] = s[t] - v;
}

__global__ __launch_bounds__(256) void scan3_kernel(int* __restrict__ dst,
                                                    const int* __restrict__ bscan,
                                                    int m) {
  const int base = blockIdx.x * SCAN_B;
  const int add = bscan[blockIdx.x];
  for (int i = threadIdx.x; i < SCAN_B; i += 256) {
    const int idx = base + i;
    if (idx < m) dst[idx] += add;
  }
}

__global__ __launch_bounds__(256) void scatterC_kernel(
    const int* __restrict__ ei, const float* __restrict__ ew,
    const int* __restrict__ offs, int2* __restrict__ pairs, int E, int nbuck,
    int nch) {
  __shared__ int cur[512];
  const int c = blockIdx.x;
  for (int b = threadIdx.x; b < nbuck; b += 256) cur[b] = offs[b * nch + c];
  __syncthreads();
  const int base = c * CHUNK;
  for (int i = threadIdx.x; i < CHUNK; i += 256) {
    const int e = base + i;
    if (e >= E) break;
    const int s = ei[e];
    const int d = ei[E + e];
    const float w = ew[e];
    const int pos = atomicAdd(&cur[d >> 8], 1);
    pairs[pos] = make_int2(s | ((d & (DPB - 1)) << 17), __float_as_int(w));
  }
}

__global__ __launch_bounds__(256) void bucketD_kernel(const int* __restrict__ offs,
                                                      int2* __restrict__ pairs,
                                                      int* __restrict__ rowptr, int n,
                                                      int E, int nbuck, int nch) {
  __shared__ int2 stage[BMAX];
  __shared__ int h[DPB];
  __shared__ int s[DPB];
  __shared__ int cur[DPB];
  const int b = blockIdx.x;
  const int t = threadIdx.x;
  if (b == 0 && t == 0) rowptr[n] = E;
  const int base = offs[b * nch];
  const int end = (b + 1 < nbuck) ? offs[(b + 1) * nch] : E;
  const int cnt = end - base;

  for (int i = t; i < DPB; i += 256) h[i] = 0;
  __syncthreads();
  for (int i = t; i < cnt; i += 256) {
    const int2 p = pairs[base + i];
    atomicAdd(&h[(p.x >> 17) & (DPB - 1)], 1);
  }
  __syncthreads();
  const int own = h[t];
  s[t] = own;
  __syncthreads();
  for (int off = 1; off < 256; off <<= 1) {
    int val = (t >= off) ? s[t - off] : 0;
    __syncthreads();
    s[t] += val;
    __syncthreads();
  }
  const int excl = s[t] - own;
  cur[t] = excl;
  const int dst = b * DPB + t;
  if (dst < n) rowptr[dst] = base + excl;
  __syncthreads();
  for (int i = t; i < cnt; i += 256) {
    const int2 p = pairs[base + i];
    const int r = atomicAdd(&cur[(p.x >> 17) & (DPB - 1)], 1);
    if (r < BMAX) stage[r] = make_int2(p.x & 0x1FFFF, p.y);
  }
  __syncthreads();
  const int lim = cnt < BMAX ? cnt : BMAX;
  for (int i = t; i < lim; i += 256) pairs[base + i] = stage[i];
}

// ---------- fused pull + next-layer GEMM, fp16 tables ----------
// Quad (4 lanes) per node: lane-strided edge gather (fp16 rows, fp32 acc),
// quad shfl_xor reduce, +agg-bias, then each lane emits 4 columns of h@W.
template <int PIN, int CIN, int COUT, int POUT, bool AGG_BIAS, bool OUT_BIAS,
          bool IDENT, typename TOUT>
__global__ __launch_bounds__(256) void pull_gemm_kernel(
    const int* __restrict__ rowptr, const int2* __restrict__ pairs,
    const __half* __restrict__ sup, const float* __restrict__ bagg,
    const float* __restrict__ W, const float* __restrict__ bout,
    TOUT* __restrict__ outp, int n) {
  __shared__ float sW[IDENT ? 1 : CIN * 16];
  __shared__ float sba[16];
  __shared__ float sbo[16];
  const int tt = threadIdx.x;
  if constexpr (!IDENT) {
    for (int i = tt; i < CIN * 16; i += 256) {
      const int k = i >> 4, j = i & 15;
      sW[i] = (j < COUT) ? W[k * COUT + j] : 0.f;
    }
  }
  if constexpr (AGG_BIAS)
    if (tt < CIN) sba[tt] = bagg[tt];
  if constexpr (OUT_BIAS)
    if (tt < COUT) sbo[tt] = bout[tt];
  __syncthreads();

  const int t = blockIdx.x * 256 + tt;
  const int v = t >> 2;
  const int lane = t & 3;
  if (v >= n) return;
  const int beg = rowptr[v];
  const int end = rowptr[v + 1];

  float acc[CIN];
#pragma unroll
  for (int c = 0; c < CIN; ++c) acc[c] = 0.f;

  for (int i = beg + lane; i < end; i += 4) {
    const int2 p = pairs[i];
    const float w = __int_as_float(p.y);
    const __half* hr = sup + (size_t)p.x * PIN;
    float hv[CIN];
    if constexpr (PIN == 16) {
      union { uint4 u; __half2 h[4]; } a;
      union { uint2 u; __half2 h[2]; } b;
      a.u = *(const uint4*)hr;
      b.u = *(const uint2*)(hr + 8);
#pragma unroll
      for (int g = 0; g < CIN / 2; ++g) {
        float2 f = __half22float2(g < 4 ? a.h[g] : b.h[g - 4]);
        hv[2 * g] = f.x;
        hv[2 * g + 1] = f.y;
      }
    } else if constexpr (PIN == 8) {
      union { uint4 u; __half2 h[4]; } a;
      a.u = *(const uint4*)hr;
#pragma unroll
      for (int g = 0; g < CIN / 2; ++g) {
        float2 f = __half22float2(a.h[g]);
        hv[2 * g] = f.x;
        hv[2 * g + 1] = f.y;
      }
    } else {  // PIN == 4
      union { uint2 u; __half2 h[2]; } a;
      a.u = *(const uint2*)hr;
#pragma unroll
      for (int g = 0; g < CIN / 2; ++g) {
        float2 f = __half22float2(a.h[g]);
        hv[2 * g] = f.x;
        hv[2 * g + 1] = f.y;
      }
    }
#pragma unroll
    for (int c = 0; c < CIN; ++c) acc[c] = fmaf(w, hv[c], acc[c]);
  }
#pragma unroll
  for (int c = 0; c < CIN; ++c) {
    acc[c] += __shfl_xor(acc[c], 1);
    acc[c] += __shfl_xor(acc[c], 2);
    if constexpr (AGG_BIAS) acc[c] += sba[c];
  }

  if constexpr (IDENT) {
    if (lane == 0) {
      union { uint2 u; __half2 h[2]; } o;
      o.h[0] = __floats2half2_rn(acc[0], acc[1]);
      o.h[1] = __floats2half2_rn(acc[2], acc[3]);
      *(uint2*)((__half*)outp + (size_t)v * POUT) = o.u;
    }
  } else {
    if (lane * 4 < POUT) {
      const int col = lane * 4;
      float r[4];
#pragma unroll
      for (int j = 0; j < 4; ++j) {
        float a = OUT_BIAS ? sbo[col + j] : 0.f;
#pragma unroll
        for (int k = 0; k < CIN; ++k) a = fmaf(acc[k], sW[k * 16 + col + j], a);
        r[j] = a;
      }
      if constexpr (sizeof(TOUT) == 2) {
        union { uint2 u; __half2 h[2]; } o;
        o.h[0] = __floats2half2_rn(r[0], r[1]);
        o.h[1] = __floats2half2_rn(r[2], r[3]);
        *(uint2*)((__half*)outp + (size_t)v * POUT + col) = o.u;
      } else {
        float4 o;
        o.x = r[0]; o.y = r[1]; o.z = r[2]; o.w = r[3];
        *(float4*)((float*)outp + (size_t)v * POUT + col) = o;
      }
    }
  }
}

extern "C" void kernel_launch(void* const* d_in, const int* in_sizes, int n_in,
                              void* d_out, int out_size, void* d_ws,
                              size_t ws_size, hipStream_t stream) {
  const float* x = (const float*)d_in[0];
  const int* ei = (const int*)d_in[1];
  const float* ew = (const float*)d_in[2];
  const float* W1 = (const float*)d_in[3];
  const float* b1 = (const float*)d_in[4];
  const float* W2 = (const float*)d_in[5];
  const float* b2 = (const float*)d_in[6];
  const float* W3 = (const float*)d_in[7];
  const float* b3 = (const float*)d_in[8];
  const float* W4 = (const float*)d_in[9];
  const float* b4 = (const float*)d_in[10];
  const float* W5 = (const float*)d_in[11];
  const float* b5 = (const float*)d_in[12];
  const float* W6 = (const float*)d_in[13];
  const float* b6 = (const float*)d_in[14];
  float* out = (float*)d_out;

  const int n = in_sizes[0] / NF;  // 100000
  const int E = in_sizes[2];       // 3200000

  const int nbuck = (n + DPB - 1) / DPB;    // 391
  const int nch = (E + CHUNK - 1) / CHUNK;  // 196
  const int M = nbuck * nch;                // 76636
  const int Mpad = (M + 3) & ~3;

  // workspace layout (16B aligned); A/B are fp16 pitch-16 tables
  __half* A = (__half*)d_ws;              // n*16 halves
  __half* B = A + (size_t)n * 16;         // n*16 halves
  int* cnt = (int*)(B + (size_t)n * 16);  // Mpad
  int* offs = cnt + Mpad;                 // Mpad
  int* bsums = offs + Mpad;               // 256
  int* bscan = bsums + 256;               // 256
  int* rowptr = bscan + 256;              // n+1
  uintptr_t up = (uintptr_t)(rowptr + n + 1);
  up = (up + 15) & ~(uintptr_t)15;
  int2* pairs = (int2*)up;                // E

  const int gn256 = (n + 255) / 256;          // 391
  const int gq = ((n * 4) + 255) / 256;       // 1563 quad blocks
  const int nsb = (M + SCAN_B - 1) / SCAN_B;  // 75

  // ---- K1: countA (blocks 0..nch) + gemm_big (blocks nch..) concurrently ----
  gemm_big_count_kernel<12>
      <<<nch + gn256, 256, 0, stream>>>(x, W1, A, n, ei, cnt, E, nbuck, nch);
  // ---- scans + partition + per-bucket sort (zero global atomics) ----
  scan1_kernel<<<nsb, 256, 0, stream>>>(cnt, offs, bsums, M);
  scan2_kernel<<<1, 256, 0, stream>>>(bsums, bscan, nsb);
  scan3_kernel<<<nsb, 256, 0, stream>>>(offs, bscan, M);
  scatterC_kernel<<<nch, 256, 0, stream>>>(ei, ew, offs, pairs, E, nbuck, nch);
  bucketD_kernel<<<nbuck, 256, 0, stream>>>(offs, pairs, rowptr, n, E, nbuck, nch);

  // ---- fused: h_k = pull(sup_k)+b_k ; sup_{k+1} = h_k @ W_{k+1} (fp16 tables) ----
  // F1: pull(A,12)+b1 @W2(12x10) -> B pitch16
  pull_gemm_kernel<16, 12, 10, 16, true, false, false, __half>
      <<<gq, 256, 0, stream>>>(rowptr, pairs, A, b1, W2, nullptr, B, n);
  // F2: pull(B,10)+b2 @W3(10x8) -> A pitch8
  pull_gemm_kernel<16, 10, 8, 8, true, false, false, __half>
      <<<gq, 256, 0, stream>>>(rowptr, pairs, B, b2, W3, nullptr, A, n);
  // F3: pull(A,8)+b3 @W4(8x6) -> B pitch8
  pull_gemm_kernel<8, 8, 6, 8, true, false, false, __half>
      <<<gq, 256, 0, stream>>>(rowptr, pairs, A, b3, W4, nullptr, B, n);
  // F4: pull(B,6)+b4 @W5(6x4) -> A pitch4
  pull_gemm_kernel<8, 6, 4, 4, true, false, false, __half>
      <<<gq, 256, 0, stream>>>(rowptr, pairs, B, b4, W5, nullptr, A, n);
  // F5: h5 = pull(A,4)+b5 -> B pitch4 (identity)
  pull_gemm_kernel<4, 4, 4, 4, true, false, true, __half>
      <<<gq, 256, 0, stream>>>(rowptr, pairs, A, b5, nullptr, nullptr, B, n);
  // F6: agg6 = pull(B,4); out = agg6@W6 + b6 (fp32 output)
  pull_gemm_kernel<4, 4, 16, 16, false, true, false, float>
      <<<gq, 256, 0, stream>>>(rowptr, pairs, B, nullptr, W6, b6, out, n);
}